// Round 1
// baseline (557.322 us; speedup 1.0000x reference)
//
#include <hip/hip_runtime.h>
#include <hip/hip_bf16.h>

// Problem constants (fixed by reference setup_inputs)
constexpr int BS = 64, C = 256, NH = 4, DH = 64, T = 6, D = 192;
constexpr int HH = 56, WW = 56, HW = HH * WW;     // 3136
constexpr int NT = 112, NCH = HW / NT;            // 28 exact chunks
constexpr float SCALE = 0.125f;                   // dh^-0.5
constexpr float LN_EPS = 1e-5f;

// ---------------------------------------------------------------------------
// Kernel 1: q = tokens @ q_w^T + q_b ; gate = h_sigmoid(tokens @ alpha_w^T + alpha_b)*2
// grid = T*BS blocks, 256 threads (one per output channel c)
// ---------------------------------------------------------------------------
__global__ __launch_bounds__(256) void qalpha_kernel(
    const float* __restrict__ tokens,   // [T,BS,D]
    const float* __restrict__ q_w,      // [C,D]
    const float* __restrict__ q_b,      // [C]
    const float* __restrict__ alpha_w,  // [C,D]
    const float* __restrict__ alpha_b,  // [C]
    float* __restrict__ q_ws,           // [T,BS,C]
    float* __restrict__ alp_ws)         // [T,BS,C]
{
    int tb = blockIdx.x;           // t*BS + b
    int c  = threadIdx.x;
    __shared__ float tok_s[D];
    for (int i = c; i < D; i += 256) tok_s[i] = tokens[tb * D + i];
    __syncthreads();

    const float* qr = q_w + (size_t)c * D;
    const float* ar = alpha_w + (size_t)c * D;
    float qa = 0.f, aa = 0.f;
#pragma unroll 8
    for (int d = 0; d < D; ++d) {
        float tv = tok_s[d];
        qa += tv * qr[d];
        aa += tv * ar[d];
    }
    qa += q_b[c];
    aa += alpha_b[c] + 3.0f;
    aa = fminf(fmaxf(aa, 0.0f), 6.0f) * (2.0f / 6.0f);  // h_sigmoid * ALPHA_SCALE
    q_ws[(size_t)tb * C + c] = qa;
    alp_ws[(size_t)tb * C + c] = aa;
}

// ---------------------------------------------------------------------------
// Kernel 2: fused single-pass over features per (b,h):
//   - attn scores (written to out, pre-softmax, scaled)
//   - flash-style online softmax + PV accumulation
//   - mlp branch partial sums over HW
//   - gate + combine -> gated_ws[t,b,c]
// grid = BS*NH = 256 blocks, 384 threads (6 waves; wave w owns token t=w)
// ---------------------------------------------------------------------------
__global__ __launch_bounds__(384) void fused_attn_mlp(
    const float* __restrict__ feat,    // [BS,C,HW]
    const float* __restrict__ mlp_w,   // [T,HW]
    const float* __restrict__ mlp_b,   // [T]
    const float* __restrict__ q_ws,    // [T,BS,C]
    const float* __restrict__ alp_ws,  // [T,BS,C]
    float* __restrict__ out_attn,      // [BS,NH,T,HW]
    float* __restrict__ gated_ws)      // [T,BS,C]
{
    int b = blockIdx.x / NH, h = blockIdx.x % NH;
    int tid = threadIdx.x;
    int wave = tid >> 6, lane = tid & 63;

    __shared__ float qs[T][DH];          // 1.5 KB
    __shared__ float fch[DH][NT + 1];    // 28.9 KB, stride 113 -> conflict-free both axes
    __shared__ float st[T][NT];          // 2.6 KB scores chunk
    __shared__ float pt[T][NT];          // 2.6 KB exp(scores) chunk
    __shared__ float mw[T][NT];          // 2.6 KB mlp_w chunk
    __shared__ float m_s[T], l_s[T], al_s[T];

    // stage q fragments for this (b,h)
    for (int i = tid; i < T * DH; i += 384) {
        int t = i / DH, c = i % DH;
        qs[t][c] = q_ws[((size_t)t * BS + b) * C + h * DH + c];
    }
    if (tid < T) { m_s[tid] = -1e30f; l_s[tid] = 0.f; }

    const int t_own = wave;       // each thread owns one (t, c) pair
    const int c_own = lane;
    float mlp_acc = 0.f, o_acc = 0.f;

    const float* fbase = feat + ((size_t)b * C + h * DH) * HW;
    float* out_base = out_attn + ((size_t)(b * NH + h) * T) * HW;
    __syncthreads();

    for (int ch = 0; ch < NCH; ++ch) {
        const int n0 = ch * NT;
        // ---- load f chunk [DH x NT] via float4, and mlp_w chunk [T x NT]
        for (int i = tid; i < DH * (NT / 4); i += 384) {
            int c = i / (NT / 4), v = i % (NT / 4);
            float4 f4 = *(const float4*)(fbase + (size_t)c * HW + n0 + 4 * v);
            fch[c][4 * v + 0] = f4.x; fch[c][4 * v + 1] = f4.y;
            fch[c][4 * v + 2] = f4.z; fch[c][4 * v + 3] = f4.w;
        }
        for (int i = tid; i < T * NT; i += 384) {
            int t = i / NT, n = i % NT;
            mw[t][n] = mlp_w[(size_t)t * HW + n0 + n];
        }
        __syncthreads();

        // ---- scores: s[t][n] = SCALE * sum_c q[t][c] * f[c][n]; write to out
        for (int j = tid; j < T * NT; j += 384) {
            int t = j / NT, n = j % NT;
            float acc = 0.f;
#pragma unroll
            for (int c = 0; c < DH; ++c) acc += qs[t][c] * fch[c][n];
            acc *= SCALE;
            st[t][n] = acc;
            out_base[(size_t)t * HW + n0 + n] = acc;
        }
        // ---- mlp branch partial: each thread owns (t_own, c_own)
        {
            float acc = 0.f;
#pragma unroll 4
            for (int n = 0; n < NT; ++n) acc += fch[c_own][n] * mw[t_own][n];
            mlp_acc += acc;
        }
        __syncthreads();

        // ---- online softmax: wave t reduces its row of st
        {
            int t = wave;
            float mloc = -1e30f;
            for (int n = lane; n < NT; n += 64) mloc = fmaxf(mloc, st[t][n]);
            for (int off = 32; off; off >>= 1) mloc = fmaxf(mloc, __shfl_down(mloc, off));
            mloc = __shfl(mloc, 0);
            float m_old = m_s[t];
            float m_new = fmaxf(m_old, mloc);
            float ssum = 0.f;
            for (int n = lane; n < NT; n += 64) {
                float p = __expf(st[t][n] - m_new);
                pt[t][n] = p;
                ssum += p;
            }
            for (int off = 32; off; off >>= 1) ssum += __shfl_down(ssum, off);
            if (lane == 0) {
                float alpha = __expf(m_old - m_new);
                l_s[t] = l_s[t] * alpha + __shfl(ssum, 0);
                m_s[t] = m_new;
                al_s[t] = alpha;
            }
        }
        __syncthreads();

        // ---- PV accumulate with rescale: o[t][d] = o*alpha + sum_n p[t][n]*f[d][n]
        {
            float al = al_s[t_own];
            float acc = 0.f;
#pragma unroll 4
            for (int n = 0; n < NT; ++n) acc += pt[t_own][n] * fch[c_own][n];
            o_acc = o_acc * al + acc;
        }
        __syncthreads();   // fch/st/pt reused next chunk
    }

    // ---- combine: gated = (mlp + mlp_b + attn_out) * gate
    {
        float o = o_acc / l_s[t_own];
        float val = mlp_acc + mlp_b[t_own] + o;
        size_t idx = ((size_t)t_own * BS + b) * C + h * DH + c_own;
        gated_ws[idx] = val * alp_ws[idx];
    }
}

// ---------------------------------------------------------------------------
// Kernel 3: proj + residual + LayerNorm.  grid = T*BS blocks, 192 threads (d)
// ---------------------------------------------------------------------------
__global__ __launch_bounds__(192) void proj_ln_kernel(
    const float* __restrict__ tokens,   // [T,BS,D]
    const float* __restrict__ gated,    // [T,BS,C]
    const float* __restrict__ proj_w,   // [D,C]
    const float* __restrict__ proj_b,   // [D]
    const float* __restrict__ ln_g,     // [D]
    const float* __restrict__ ln_b,     // [D]
    float* __restrict__ out_tok)        // [T,BS,D]
{
    int tb = blockIdx.x;
    int d  = threadIdx.x;
    __shared__ float g_s[C];
    __shared__ float r1[3], r2[3];
    for (int i = d; i < C; i += 192) g_s[i] = gated[(size_t)tb * C + i];
    __syncthreads();

    float acc = proj_b[d] + tokens[(size_t)tb * D + d];
    const float* pr = proj_w + (size_t)d * C;
#pragma unroll 8
    for (int c = 0; c < C; ++c) acc += g_s[c] * pr[c];

    // LayerNorm over D=192 (3 waves)
    float s1 = acc, s2 = acc * acc;
    for (int off = 32; off; off >>= 1) { s1 += __shfl_down(s1, off); s2 += __shfl_down(s2, off); }
    int wave = d >> 6, lane = d & 63;
    if (lane == 0) { r1[wave] = s1; r2[wave] = s2; }
    __syncthreads();
    float sum1 = r1[0] + r1[1] + r1[2];
    float sum2 = r2[0] + r2[1] + r2[2];
    float mu = sum1 * (1.0f / D);
    float var = sum2 * (1.0f / D) - mu * mu;
    float inv = rsqrtf(var + LN_EPS);
    out_tok[(size_t)tb * D + d] = (acc - mu) * inv * ln_g[d] + ln_b[d];
}

// ---------------------------------------------------------------------------
extern "C" void kernel_launch(void* const* d_in, const int* in_sizes, int n_in,
                              void* d_out, int out_size, void* d_ws, size_t ws_size,
                              hipStream_t stream) {
    const float* features = (const float*)d_in[0];
    const float* tokens   = (const float*)d_in[1];
    const float* mlp_w    = (const float*)d_in[2];
    const float* mlp_b    = (const float*)d_in[3];
    const float* q_w      = (const float*)d_in[4];
    const float* q_b      = (const float*)d_in[5];
    const float* alpha_w  = (const float*)d_in[6];
    const float* alpha_b  = (const float*)d_in[7];
    const float* proj_w   = (const float*)d_in[8];
    const float* proj_b   = (const float*)d_in[9];
    const float* ln_g     = (const float*)d_in[10];
    const float* ln_b     = (const float*)d_in[11];

    float* out_tok  = (float*)d_out;                   // [T,BS,D] = 73728
    float* out_attn = (float*)d_out + T * BS * D;      // [BS,NH,T,HW]

    float* q_ws     = (float*)d_ws;                    // T*BS*C
    float* alp_ws   = q_ws + T * BS * C;               // T*BS*C
    float* gated_ws = alp_ws + T * BS * C;             // T*BS*C

    qalpha_kernel<<<T * BS, 256, 0, stream>>>(
        tokens, q_w, q_b, alpha_w, alpha_b, q_ws, alp_ws);

    fused_attn_mlp<<<BS * NH, 384, 0, stream>>>(
        features, mlp_w, mlp_b, q_ws, alp_ws, out_attn, gated_ws);

    proj_ln_kernel<<<T * BS, 192, 0, stream>>>(
        tokens, gated_ws, proj_w, proj_b, ln_g, ln_b, out_tok);
}

// Round 2
// 483.508 us; speedup vs baseline: 1.1527x; 1.1527x over previous
//
#include <hip/hip_runtime.h>
#include <hip/hip_bf16.h>

// Problem constants (fixed by reference setup_inputs)
constexpr int BS = 64, C = 256, NH = 4, DH = 64, T = 6, D = 192;
constexpr int HW = 3136;
constexpr int NT = 112, NCH = 28;        // chunk size / count over HW
constexpr int S = 7, CPB = 4;            // HW splits per (b,h), chunks per split
constexpr int PNT = 116;                 // padded chunk stride (float4-aligned, uniform banks)
constexpr float SCALE = 0.125f;          // dh^-0.5
constexpr float LN_EPS = 1e-5f;

// ---------------------------------------------------------------------------
// Kernel 1: q / gate. grid = BS blocks (per b), 256 threads (per channel c).
// Weight rows read once per block (float4), reused across all T=6 tokens.
// ---------------------------------------------------------------------------
__global__ __launch_bounds__(256) void qalpha_kernel(
    const float* __restrict__ tokens,   // [T,BS,D]
    const float* __restrict__ q_w,      // [C,D]
    const float* __restrict__ q_b,      // [C]
    const float* __restrict__ alpha_w,  // [C,D]
    const float* __restrict__ alpha_b,  // [C]
    float* __restrict__ q_ws,           // [T,BS,C]
    float* __restrict__ alp_ws)         // [T,BS,C]
{
    int b = blockIdx.x;
    int c = threadIdx.x;
    __shared__ float tok_s[T][D];
    for (int i = c; i < T * (D / 4); i += 256) {
        int t = i / (D / 4), v = i % (D / 4);
        *(float4*)&tok_s[t][4 * v] =
            *(const float4*)&tokens[((size_t)t * BS + b) * D + 4 * v];
    }
    __syncthreads();

    const float4* qr = (const float4*)(q_w + (size_t)c * D);
    const float4* ar = (const float4*)(alpha_w + (size_t)c * D);
    float accq[T] = {0, 0, 0, 0, 0, 0};
    float acca[T] = {0, 0, 0, 0, 0, 0};
    for (int v = 0; v < D / 4; ++v) {
        float4 qw4 = qr[v], aw4 = ar[v];
#pragma unroll
        for (int t = 0; t < T; ++t) {
            float4 t4 = *(const float4*)&tok_s[t][4 * v];
            accq[t] += qw4.x * t4.x + qw4.y * t4.y + qw4.z * t4.z + qw4.w * t4.w;
            acca[t] += aw4.x * t4.x + aw4.y * t4.y + aw4.z * t4.z + aw4.w * t4.w;
        }
    }
    float qb = q_b[c], ab = alpha_b[c];
#pragma unroll
    for (int t = 0; t < T; ++t) {
        size_t idx = ((size_t)t * BS + b) * C + c;
        q_ws[idx] = accq[t] + qb;
        float aa = acca[t] + ab + 3.0f;
        alp_ws[idx] = fminf(fmaxf(aa, 0.0f), 6.0f) * (2.0f / 6.0f);
    }
}

// ---------------------------------------------------------------------------
// Kernel 2: fused attention + mlp branch, split over HW.
// grid = BS*NH*S = 1792 blocks; block = (b, h, split of 4 chunks).
// 384 threads = 6 waves; wave w owns token t=w for softmax/mlp/PV.
// Emits flash-style partials (m, l, O, mlp) per split.
// ---------------------------------------------------------------------------
__global__ __launch_bounds__(384) void fused_attn_mlp(
    const float* __restrict__ feat,     // [BS,C,HW]
    const float* __restrict__ mlp_w,    // [T,HW]
    const float* __restrict__ q_ws,     // [T,BS,C]
    float* __restrict__ out_attn,       // [BS,NH,T,HW] (pre-softmax scores)
    float* __restrict__ o_part,         // [BS*NH*S][T][DH]
    float* __restrict__ mlp_part,       // [BS*NH*S][T][DH]
    float* __restrict__ ml_part)        // [BS*NH*S][T][2]
{
    int bh = blockIdx.x / S, sp = blockIdx.x % S;
    int b = bh / NH, h = bh % NH;
    int tid = threadIdx.x;
    int wave = tid >> 6, lane = tid & 63;

    __shared__ float qs[T][DH];          // 1.5 KB
    __shared__ float fch[DH][PNT];       // 29.7 KB
    __shared__ float st[T][PNT];         // 2.8 KB
    __shared__ float pt[T][PNT];         // 2.8 KB
    __shared__ float mwc[T][PNT];        // 2.8 KB
    __shared__ float m_s[T], l_s[T], al_s[T];

    for (int i = tid; i < T * DH; i += 384) {
        int t = i / DH, c2 = i % DH;
        qs[t][c2] = q_ws[((size_t)t * BS + b) * C + h * DH + c2];
    }
    if (tid < T) { m_s[tid] = -3e38f; l_s[tid] = 0.f; }

    const float* fbase = feat + ((size_t)b * C + h * DH) * HW;
    float* obase = out_attn + ((size_t)bh * T) * HW;

    const int t_own = wave, c_own = lane;
    float mlp_acc = 0.f, o_acc = 0.f;
    __syncthreads();

    for (int cc = 0; cc < CPB; ++cc) {
        const int n0 = (sp * CPB + cc) * NT;
        // ---- stage f chunk [DH x NT] + mlp_w chunk [T x NT], float4
        for (int i = tid; i < DH * (NT / 4); i += 384) {
            int c2 = i / (NT / 4), v = i % (NT / 4);
            *(float4*)&fch[c2][4 * v] =
                *(const float4*)&fbase[(size_t)c2 * HW + n0 + 4 * v];
        }
        for (int i = tid; i < T * (NT / 4); i += 384) {
            int t = i / (NT / 4), v = i % (NT / 4);
            *(float4*)&mwc[t][4 * v] =
                *(const float4*)&mlp_w[(size_t)t * HW + n0 + 4 * v];
        }
        __syncthreads();

        // ---- scores: float2 per thread, 336 active threads
        if (tid < 336) {
            int t = tid / 56, n = 2 * (tid % 56);
            float ax = 0.f, ay = 0.f;
#pragma unroll 8
            for (int c2 = 0; c2 < DH; ++c2) {
                float2 f2 = *(const float2*)&fch[c2][n];
                float qv = qs[t][c2];
                ax += qv * f2.x;
                ay += qv * f2.y;
            }
            ax *= SCALE; ay *= SCALE;
            st[t][n] = ax; st[t][n + 1] = ay;
            *(float2*)&obase[(size_t)t * HW + n0 + n] = make_float2(ax, ay);
        }
        // ---- mlp partial (reads fch+mwc only; independent of st writes)
        {
            float acc = 0.f;
#pragma unroll
            for (int v = 0; v < NT / 4; ++v) {
                float4 f4 = *(const float4*)&fch[c_own][4 * v];
                float4 w4 = *(const float4*)&mwc[t_own][4 * v];
                acc += f4.x * w4.x + f4.y * w4.y + f4.z * w4.z + f4.w * w4.w;
            }
            mlp_acc += acc;
        }
        __syncthreads();

        // ---- online softmax: wave t reduces its row
        {
            int t = wave;
            float mloc = -3e38f;
            for (int n = lane; n < NT; n += 64) mloc = fmaxf(mloc, st[t][n]);
#pragma unroll
            for (int off = 32; off; off >>= 1) mloc = fmaxf(mloc, __shfl_down(mloc, off));
            mloc = __shfl(mloc, 0);
            float m_old = m_s[t], m_new = fmaxf(m_old, mloc);
            float ssum = 0.f;
            for (int n = lane; n < NT; n += 64) {
                float p = __expf(st[t][n] - m_new);
                pt[t][n] = p;
                ssum += p;
            }
#pragma unroll
            for (int off = 32; off; off >>= 1) ssum += __shfl_down(ssum, off);
            if (lane == 0) {
                float alpha = __expf(m_old - m_new);
                l_s[t] = l_s[t] * alpha + ssum;
                m_s[t] = m_new;
                al_s[t] = alpha;
            }
        }
        __syncthreads();

        // ---- PV accumulate with rescale
        {
            float al = al_s[t_own];
            float acc = 0.f;
#pragma unroll
            for (int v = 0; v < NT / 4; ++v) {
                float4 f4 = *(const float4*)&fch[c_own][4 * v];
                float4 p4 = *(const float4*)&pt[t_own][4 * v];
                acc += f4.x * p4.x + f4.y * p4.y + f4.z * p4.z + f4.w * p4.w;
            }
            o_acc = o_acc * al + acc;
        }
        __syncthreads();   // fch/st/pt/mwc reused next chunk
    }

    size_t pidx = ((size_t)blockIdx.x * T + t_own) * DH + c_own;
    o_part[pidx] = o_acc;
    mlp_part[pidx] = mlp_acc;
    if (tid < 2 * T) {
        int t = tid >> 1;
        ml_part[((size_t)blockIdx.x * T + t) * 2 + (tid & 1)] =
            (tid & 1) ? l_s[t] : m_s[t];
    }
}

// ---------------------------------------------------------------------------
// Kernel 3: merge split partials -> gated[t,b,c].
// grid = T*BS blocks, 256 threads (c).
// ---------------------------------------------------------------------------
__global__ __launch_bounds__(256) void merge_kernel(
    const float* __restrict__ o_part,
    const float* __restrict__ mlp_part,
    const float* __restrict__ ml_part,
    const float* __restrict__ mlp_b,    // [T]
    const float* __restrict__ alp_ws,   // [T,BS,C]
    float* __restrict__ gated_ws)       // [T,BS,C]
{
    int tb = blockIdx.x;
    int t = tb / BS, b = tb % BS;
    int c = threadIdx.x;
    int h = c >> 6, cl = c & 63;
    int bh = b * NH + h;

    float m[S], l[S];
    float M = -3e38f;
#pragma unroll
    for (int s = 0; s < S; ++s) {
        size_t blk = (size_t)(bh * S + s);
        m[s] = ml_part[(blk * T + t) * 2 + 0];
        l[s] = ml_part[(blk * T + t) * 2 + 1];
        M = fmaxf(M, m[s]);
    }
    float L = 0.f, O = 0.f, MLP = 0.f;
#pragma unroll
    for (int s = 0; s < S; ++s) {
        float w = __expf(m[s] - M);
        size_t blk = (size_t)(bh * S + s);
        size_t pidx = (blk * T + t) * DH + cl;
        L += l[s] * w;
        O += o_part[pidx] * w;
        MLP += mlp_part[pidx];
    }
    size_t idx = (size_t)tb * C + c;
    gated_ws[idx] = (MLP + mlp_b[t] + O / L) * alp_ws[idx];
}

// ---------------------------------------------------------------------------
// Kernel 4: proj + residual + LayerNorm. grid = T*BS blocks, 192 threads (d).
// ---------------------------------------------------------------------------
__global__ __launch_bounds__(192) void proj_ln_kernel(
    const float* __restrict__ tokens,   // [T,BS,D]
    const float* __restrict__ gated,    // [T,BS,C]
    const float* __restrict__ proj_w,   // [D,C]
    const float* __restrict__ proj_b,   // [D]
    const float* __restrict__ ln_g,     // [D]
    const float* __restrict__ ln_b,     // [D]
    float* __restrict__ out_tok)        // [T,BS,D]
{
    int tb = blockIdx.x;
    int d  = threadIdx.x;
    __shared__ float g_s[C];
    __shared__ float r1[3], r2[3];
    for (int i = d; i < C / 4; i += 192)
        *(float4*)&g_s[4 * i] = *(const float4*)&gated[(size_t)tb * C + 4 * i];
    __syncthreads();

    float acc = proj_b[d] + tokens[(size_t)tb * D + d];
    const float4* pr = (const float4*)(proj_w + (size_t)d * C);
#pragma unroll 8
    for (int v = 0; v < C / 4; ++v) {
        float4 w4 = pr[v];
        float4 g4 = *(const float4*)&g_s[4 * v];
        acc += w4.x * g4.x + w4.y * g4.y + w4.z * g4.z + w4.w * g4.w;
    }

    float s1 = acc, s2 = acc * acc;
#pragma unroll
    for (int off = 32; off; off >>= 1) { s1 += __shfl_down(s1, off); s2 += __shfl_down(s2, off); }
    int wave = d >> 6, lane = d & 63;
    if (lane == 0) { r1[wave] = s1; r2[wave] = s2; }
    __syncthreads();
    float sum1 = r1[0] + r1[1] + r1[2];
    float sum2 = r2[0] + r2[1] + r2[2];
    float mu = sum1 * (1.0f / D);
    float var = sum2 * (1.0f / D) - mu * mu;
    float inv = rsqrtf(var + LN_EPS);
    out_tok[(size_t)tb * D + d] = (acc - mu) * inv * ln_g[d] + ln_b[d];
}

// ---------------------------------------------------------------------------
extern "C" void kernel_launch(void* const* d_in, const int* in_sizes, int n_in,
                              void* d_out, int out_size, void* d_ws, size_t ws_size,
                              hipStream_t stream) {
    const float* features = (const float*)d_in[0];
    const float* tokens   = (const float*)d_in[1];
    const float* mlp_w    = (const float*)d_in[2];
    const float* mlp_b    = (const float*)d_in[3];
    const float* q_w      = (const float*)d_in[4];
    const float* q_b      = (const float*)d_in[5];
    const float* alpha_w  = (const float*)d_in[6];
    const float* alpha_b  = (const float*)d_in[7];
    const float* proj_w   = (const float*)d_in[8];
    const float* proj_b   = (const float*)d_in[9];
    const float* ln_g     = (const float*)d_in[10];
    const float* ln_b     = (const float*)d_in[11];

    float* out_tok  = (float*)d_out;                   // [T,BS,D]
    float* out_attn = (float*)d_out + T * BS * D;      // [BS,NH,T,HW]

    constexpr int NBLK = BS * NH * S;                  // 1792
    float* q_ws     = (float*)d_ws;                    // T*BS*C
    float* alp_ws   = q_ws + T * BS * C;               // T*BS*C
    float* gated_ws = alp_ws + T * BS * C;             // T*BS*C
    float* ml_part  = gated_ws + T * BS * C;           // NBLK*T*2
    float* o_part   = ml_part + NBLK * T * 2;          // NBLK*T*DH
    float* mlp_part = o_part + NBLK * T * DH;          // NBLK*T*DH

    qalpha_kernel<<<BS, 256, 0, stream>>>(
        tokens, q_w, q_b, alpha_w, alpha_b, q_ws, alp_ws);

    fused_attn_mlp<<<NBLK, 384, 0, stream>>>(
        features, mlp_w, q_ws, out_attn, o_part, mlp_part, ml_part);

    merge_kernel<<<T * BS, 256, 0, stream>>>(
        o_part, mlp_part, ml_part, mlp_b, alp_ws, gated_ws);

    proj_ln_kernel<<<T * BS, 192, 0, stream>>>(
        tokens, gated_ws, proj_w, proj_b, ln_g, ln_b, out_tok);
}

// Round 3
// 391.696 us; speedup vs baseline: 1.4228x; 1.2344x over previous
//
#include <hip/hip_runtime.h>
#include <hip/hip_bf16.h>

// Problem constants (fixed by reference setup_inputs)
constexpr int BS = 64, C = 256, NH = 4, DH = 64, T = 6, D = 192;
constexpr int HW = 3136;
constexpr int NT = 112;                  // chunk size over HW
constexpr int S = 7, CPB = 4;            // HW splits per (b,h), chunks per split
constexpr int PNT = 116;                 // padded stride (= 4*29: odd quads -> conflict-free b128 rows)
constexpr float SCALE = 0.125f;          // dh^-0.5
constexpr float LN_EPS = 1e-5f;

// ---------------------------------------------------------------------------
// Kernel 1: q = tokens @ q_w^T + q_b ; gate = h_sigmoid(tokens @ alpha_w^T + alpha_b)*2
// grid = BS blocks, 256 threads (per channel c); weights read once per block.
// ---------------------------------------------------------------------------
__global__ __launch_bounds__(256) void qalpha_kernel(
    const float* __restrict__ tokens,   // [T,BS,D]
    const float* __restrict__ q_w,      // [C,D]
    const float* __restrict__ q_b,      // [C]
    const float* __restrict__ alpha_w,  // [C,D]
    const float* __restrict__ alpha_b,  // [C]
    float* __restrict__ q_ws,           // [T,BS,C]
    float* __restrict__ alp_ws)         // [T,BS,C]
{
    int b = blockIdx.x;
    int c = threadIdx.x;
    __shared__ float tok_s[T][D];
    for (int i = c; i < T * (D / 4); i += 256) {
        int t = i / (D / 4), v = i % (D / 4);
        *(float4*)&tok_s[t][4 * v] =
            *(const float4*)&tokens[((size_t)t * BS + b) * D + 4 * v];
    }
    __syncthreads();

    const float4* qr = (const float4*)(q_w + (size_t)c * D);
    const float4* ar = (const float4*)(alpha_w + (size_t)c * D);
    float accq[T] = {0, 0, 0, 0, 0, 0};
    float acca[T] = {0, 0, 0, 0, 0, 0};
    for (int v = 0; v < D / 4; ++v) {
        float4 qw4 = qr[v], aw4 = ar[v];
#pragma unroll
        for (int t = 0; t < T; ++t) {
            float4 t4 = *(const float4*)&tok_s[t][4 * v];
            accq[t] += qw4.x * t4.x + qw4.y * t4.y + qw4.z * t4.z + qw4.w * t4.w;
            acca[t] += aw4.x * t4.x + aw4.y * t4.y + aw4.z * t4.z + aw4.w * t4.w;
        }
    }
    float qb = q_b[c], ab = alpha_b[c];
#pragma unroll
    for (int t = 0; t < T; ++t) {
        size_t idx = ((size_t)t * BS + b) * C + c;
        q_ws[idx] = accq[t] + qb;
        float aa = acca[t] + ab + 3.0f;
        alp_ws[idx] = fminf(fmaxf(aa, 0.0f), 6.0f) * (2.0f / 6.0f);
    }
}

// ---------------------------------------------------------------------------
// Kernel 2: fused attention + mlp branch, split over HW.
// grid = BS*NH*S = 1792 blocks; 384 threads = 6 waves.
// Register-blocked phases:
//   scores : thread=(t, n-pair), c-quad loop: 1 q-b128-bcast + 4 f-b64 per 8 FMA
//   mlp+PV : lane=c holds all 6 t accumulators; 1 f-b128 per 48 FMA (+12 bcasts)
// Emits flash partials (m, l, O, mlp) per split (block).
// ---------------------------------------------------------------------------
__global__ __launch_bounds__(384) void fused_attn_mlp(
    const float* __restrict__ feat,     // [BS,C,HW]
    const float* __restrict__ mlp_w,    // [T,HW]
    const float* __restrict__ q_ws,     // [T,BS,C]
    float* __restrict__ out_attn,       // [BS,NH,T,HW] (pre-softmax scores)
    float* __restrict__ o_part,         // [BS*NH*S][T][DH]
    float* __restrict__ mlp_part,       // [BS*NH*S][T][DH]
    float* __restrict__ ml_part)        // [BS*NH*S][T][2]
{
    int bh = blockIdx.x / S, sp = blockIdx.x % S;
    int b = bh / NH, h = bh % NH;
    int tid = threadIdx.x;
    int wave = tid >> 6, lane = tid & 63;

    __shared__ float qs[T][DH];          // 1.5 KB
    __shared__ float fch[DH][PNT];       // 29.7 KB
    __shared__ float st[T][PNT];         // 2.8 KB (scores)
    __shared__ float pp[T][PNT];         // 2.8 KB (softmax probs)
    __shared__ float mww[T][PNT];        // 2.8 KB (mlp_w chunk)
    __shared__ float m_s[T], l_s[T];
    __shared__ float al_s[8];            // padded for b128+b64 bcast read

    for (int i = tid; i < T * DH; i += 384) {
        int t = i / DH, c2 = i % DH;
        qs[t][c2] = q_ws[((size_t)t * BS + b) * C + h * DH + c2];
    }
    if (tid < T) { m_s[tid] = -3e38f; l_s[tid] = 0.f; }

    const float* fbase = feat + ((size_t)b * C + h * DH) * HW;
    float* obase = out_attn + ((size_t)bh * T) * HW;

    // per-lane accumulators: lane owns channel c=lane; partial over this
    // wave's nq-subset (stride-6 interleave); reduced across waves at end.
    float O_p[T] = {0, 0, 0, 0, 0, 0};
    float M_p[T] = {0, 0, 0, 0, 0, 0};

    // scores-phase task (first 336 threads): (t, n-pair)
    const int s_t = tid / 56, s_n = 2 * (tid % 56);

    __syncthreads();

    for (int cc = 0; cc < CPB; ++cc) {
        const int n0 = (sp * CPB + cc) * NT;
        // ---- stage f chunk [DH x NT] (float4) + mlp_w chunk [T x NT]
        for (int i = tid; i < DH * (NT / 4); i += 384) {
            int c2 = i / (NT / 4), v = i % (NT / 4);
            *(float4*)&fch[c2][4 * v] =
                *(const float4*)&fbase[(size_t)c2 * HW + n0 + 4 * v];
        }
        for (int i = tid; i < T * (NT / 4); i += 384) {
            int t = i / (NT / 4), v = i % (NT / 4);
            *(float4*)&mww[t][4 * v] =
                *(const float4*)&mlp_w[(size_t)t * HW + n0 + 4 * v];
        }
        __syncthreads();

        // ---- scores: thread (t, n-pair); c-quad loop
        if (tid < 336) {
            float ax = 0.f, ay = 0.f;
#pragma unroll 4
            for (int cq = 0; cq < DH / 4; ++cq) {
                float4 q4 = *(const float4*)&qs[s_t][4 * cq];
                float2 f0 = *(const float2*)&fch[4 * cq + 0][s_n];
                float2 f1 = *(const float2*)&fch[4 * cq + 1][s_n];
                float2 f2 = *(const float2*)&fch[4 * cq + 2][s_n];
                float2 f3 = *(const float2*)&fch[4 * cq + 3][s_n];
                ax += q4.x * f0.x + q4.y * f1.x + q4.z * f2.x + q4.w * f3.x;
                ay += q4.x * f0.y + q4.y * f1.y + q4.z * f2.y + q4.w * f3.y;
            }
            ax *= SCALE; ay *= SCALE;
            st[s_t][s_n] = ax; st[s_t][s_n + 1] = ay;
            *(float2*)&obase[(size_t)s_t * HW + n0 + s_n] = make_float2(ax, ay);
        }
        __syncthreads();

        // ---- online softmax: wave t reduces its row; writes p into pp[t][:]
        {
            int t = wave;
            float mloc = -3e38f;
            for (int n = lane; n < NT; n += 64) mloc = fmaxf(mloc, st[t][n]);
#pragma unroll
            for (int off = 32; off; off >>= 1) mloc = fmaxf(mloc, __shfl_down(mloc, off));
            mloc = __shfl(mloc, 0);
            float m_old = m_s[t], m_new = fmaxf(m_old, mloc);
            float ssum = 0.f;
            for (int n = lane; n < NT; n += 64) {
                float p = __expf(st[t][n] - m_new);
                pp[t][n] = p;
                ssum += p;
            }
#pragma unroll
            for (int off = 32; off; off >>= 1) ssum += __shfl_down(ssum, off);
            if (lane == 0) {
                float alpha = __expf(m_old - m_new);
                l_s[t] = l_s[t] * alpha + ssum;
                m_s[t] = m_new;
                al_s[t] = alpha;
            }
        }
        __syncthreads();

        // ---- mlp+PV, t-in-registers: lane=c; this wave's nq subset
        {
            float4 a03 = *(const float4*)&al_s[0];
            float al4 = al_s[4], al5 = al_s[5];
            O_p[0] *= a03.x; O_p[1] *= a03.y; O_p[2] *= a03.z; O_p[3] *= a03.w;
            O_p[4] *= al4;   O_p[5] *= al5;
            for (int nq = wave; nq < NT / 4; nq += 6) {
                float4 f4 = *(const float4*)&fch[lane][4 * nq];
#pragma unroll
                for (int t = 0; t < T; ++t) {
                    float4 p4 = *(const float4*)&pp[t][4 * nq];
                    float4 w4 = *(const float4*)&mww[t][4 * nq];
                    O_p[t] += p4.x * f4.x + p4.y * f4.y + p4.z * f4.z + p4.w * f4.w;
                    M_p[t] += w4.x * f4.x + w4.y * f4.y + w4.z * f4.z + w4.w * f4.w;
                }
            }
        }
        __syncthreads();   // fch/st/pp/mww reused next chunk
    }

    // ---- cross-wave reduction of partials through reused fch space
    float* red = &fch[0][0];                 // red_o[6][6][64] then red_m[6][6][64]
    float* red_o = red;
    float* red_m = red + 6 * T * DH;         // 4608 floats total < 64*116
#pragma unroll
    for (int t = 0; t < T; ++t) {
        red_o[(wave * T + t) * DH + lane] = O_p[t];
        red_m[(wave * T + t) * DH + lane] = M_p[t];
    }
    __syncthreads();

    {
        int t = wave;   // 6 waves <-> 6 tokens
        float o = 0.f, m = 0.f;
#pragma unroll
        for (int w = 0; w < 6; ++w) {
            o += red_o[(w * T + t) * DH + lane];
            m += red_m[(w * T + t) * DH + lane];
        }
        size_t pidx = ((size_t)blockIdx.x * T + t) * DH + lane;
        o_part[pidx] = o;
        mlp_part[pidx] = m;
    }
    if (tid < 2 * T) {
        int t = tid >> 1;
        ml_part[((size_t)blockIdx.x * T + t) * 2 + (tid & 1)] =
            (tid & 1) ? l_s[t] : m_s[t];
    }
}

// ---------------------------------------------------------------------------
// Kernel 3: merge split partials + gate + proj + residual + LayerNorm.
// grid = T*BS blocks, 256 threads. Phase 1 (c=tid<256): merge -> gated in LDS.
// Phase 2 (d=tid<192): proj row-dot + LN.
// ---------------------------------------------------------------------------
__global__ __launch_bounds__(256) void merge_proj_ln_kernel(
    const float* __restrict__ o_part,
    const float* __restrict__ mlp_part,
    const float* __restrict__ ml_part,
    const float* __restrict__ mlp_b,    // [T]
    const float* __restrict__ alp_ws,   // [T,BS,C]
    const float* __restrict__ tokens,   // [T,BS,D]
    const float* __restrict__ proj_w,   // [D,C]
    const float* __restrict__ proj_b,   // [D]
    const float* __restrict__ ln_g,     // [D]
    const float* __restrict__ ln_b,     // [D]
    float* __restrict__ out_tok)        // [T,BS,D]
{
    int tb = blockIdx.x;
    int t = tb / BS, b = tb % BS;
    int tid = threadIdx.x;
    __shared__ float g_s[C];
    __shared__ float r1[4], r2[4];

    // ---- phase 1: merge partials for channel c = tid
    {
        int c = tid;
        int h = c >> 6, cl = c & 63;
        int bh = b * NH + h;
        float m[S], l[S];
        float M = -3e38f;
#pragma unroll
        for (int s = 0; s < S; ++s) {
            size_t blk = (size_t)(bh * S + s);
            m[s] = ml_part[(blk * T + t) * 2 + 0];
            l[s] = ml_part[(blk * T + t) * 2 + 1];
            M = fmaxf(M, m[s]);
        }
        float L = 0.f, O = 0.f, MLP = 0.f;
#pragma unroll
        for (int s = 0; s < S; ++s) {
            float w = __expf(m[s] - M);
            size_t blk = (size_t)(bh * S + s);
            size_t pidx = (blk * T + t) * DH + cl;
            L += l[s] * w;
            O += o_part[pidx] * w;
            MLP += mlp_part[pidx];
        }
        size_t idx = (size_t)tb * C + c;
        g_s[c] = (MLP + mlp_b[t] + O / L) * alp_ws[idx];
    }
    __syncthreads();

    // ---- phase 2: proj + residual + LN (first 192 threads)
    if (tid < D) {
        int d = tid;
        float acc = proj_b[d] + tokens[(size_t)tb * D + d];
        const float4* pr = (const float4*)(proj_w + (size_t)d * C);
#pragma unroll 8
        for (int v = 0; v < C / 4; ++v) {
            float4 w4 = pr[v];
            float4 g4 = *(const float4*)&g_s[4 * v];
            acc += w4.x * g4.x + w4.y * g4.y + w4.z * g4.z + w4.w * g4.w;
        }

        float s1 = acc, s2 = acc * acc;
#pragma unroll
        for (int off = 32; off; off >>= 1) { s1 += __shfl_down(s1, off); s2 += __shfl_down(s2, off); }
        int wv = d >> 6, lane = d & 63;
        if (lane == 0) { r1[wv] = s1; r2[wv] = s2; }
        __syncthreads();
        float sum1 = r1[0] + r1[1] + r1[2];
        float sum2 = r2[0] + r2[1] + r2[2];
        float mu = sum1 * (1.0f / D);
        float var = sum2 * (1.0f / D) - mu * mu;
        float inv = rsqrtf(var + LN_EPS);
        out_tok[(size_t)tb * D + d] = (acc - mu) * inv * ln_g[d] + ln_b[d];
    } else {
        __syncthreads();
    }
}

// ---------------------------------------------------------------------------
extern "C" void kernel_launch(void* const* d_in, const int* in_sizes, int n_in,
                              void* d_out, int out_size, void* d_ws, size_t ws_size,
                              hipStream_t stream) {
    const float* features = (const float*)d_in[0];
    const float* tokens   = (const float*)d_in[1];
    const float* mlp_w    = (const float*)d_in[2];
    const float* mlp_b    = (const float*)d_in[3];
    const float* q_w      = (const float*)d_in[4];
    const float* q_b      = (const float*)d_in[5];
    const float* alpha_w  = (const float*)d_in[6];
    const float* alpha_b  = (const float*)d_in[7];
    const float* proj_w   = (const float*)d_in[8];
    const float* proj_b   = (const float*)d_in[9];
    const float* ln_g     = (const float*)d_in[10];
    const float* ln_b     = (const float*)d_in[11];

    float* out_tok  = (float*)d_out;                   // [T,BS,D]
    float* out_attn = (float*)d_out + T * BS * D;      // [BS,NH,T,HW]

    constexpr int NBLK = BS * NH * S;                  // 1792
    float* q_ws     = (float*)d_ws;                    // T*BS*C
    float* alp_ws   = q_ws + T * BS * C;               // T*BS*C
    float* ml_part  = alp_ws + T * BS * C;             // NBLK*T*2
    float* o_part   = ml_part + NBLK * T * 2;          // NBLK*T*DH
    float* mlp_part = o_part + NBLK * T * DH;          // NBLK*T*DH

    qalpha_kernel<<<BS, 256, 0, stream>>>(
        tokens, q_w, q_b, alpha_w, alpha_b, q_ws, alp_ws);

    fused_attn_mlp<<<NBLK, 384, 0, stream>>>(
        features, mlp_w, q_ws, out_attn, o_part, mlp_part, ml_part);

    merge_proj_ln_kernel<<<T * BS, 256, 0, stream>>>(
        o_part, mlp_part, ml_part, mlp_b, alp_ws, tokens,
        proj_w, proj_b, ln_g, ln_b, out_tok);
}

// Round 4
// 357.604 us; speedup vs baseline: 1.5585x; 1.0953x over previous
//
#include <hip/hip_runtime.h>
#include <hip/hip_bf16.h>

// Problem constants (fixed by reference setup_inputs)
constexpr int BS = 64, C = 256, NH = 4, DH = 64, T = 6, D = 192;
constexpr int HW = 3136;
constexpr int NT = 112;                  // chunk size over HW (7 n-tiles of 16)
constexpr int S = 7, CPB = 4;            // HW splits per (b,h), chunks per split
constexpr int PNF = 136;                 // fch/pw row stride (272B: 16B-aligned b128 frags)
constexpr int PNS = 116;                 // st row stride (fp32)
constexpr int QP = 72;                   // qs row stride (144B, 16B-aligned)
constexpr float SCALE = 0.125f;          // dh^-0.5
constexpr float LN_EPS = 1e-5f;

typedef short bf16x8 __attribute__((ext_vector_type(8)));
typedef float f32x4 __attribute__((ext_vector_type(4)));

__device__ inline unsigned short f2bf(float x) {
    union { float f; unsigned u; } v; v.f = x;
    unsigned r = v.u + 0x7FFFu + ((v.u >> 16) & 1u);   // RNE
    return (unsigned short)(r >> 16);
}

// ---------------------------------------------------------------------------
// Kernel 1: q = tokens @ q_w^T + q_b ; gate = h_sigmoid(tokens @ alpha_w^T + alpha_b)*2
// ---------------------------------------------------------------------------
__global__ __launch_bounds__(256) void qalpha_kernel(
    const float* __restrict__ tokens,   // [T,BS,D]
    const float* __restrict__ q_w,      // [C,D]
    const float* __restrict__ q_b,      // [C]
    const float* __restrict__ alpha_w,  // [C,D]
    const float* __restrict__ alpha_b,  // [C]
    float* __restrict__ q_ws,           // [T,BS,C]
    float* __restrict__ alp_ws)         // [T,BS,C]
{
    int b = blockIdx.x;
    int c = threadIdx.x;
    __shared__ float tok_s[T][D];
    for (int i = c; i < T * (D / 4); i += 256) {
        int t = i / (D / 4), v = i % (D / 4);
        *(float4*)&tok_s[t][4 * v] =
            *(const float4*)&tokens[((size_t)t * BS + b) * D + 4 * v];
    }
    __syncthreads();

    const float4* qr = (const float4*)(q_w + (size_t)c * D);
    const float4* ar = (const float4*)(alpha_w + (size_t)c * D);
    float accq[T] = {0, 0, 0, 0, 0, 0};
    float acca[T] = {0, 0, 0, 0, 0, 0};
    for (int v = 0; v < D / 4; ++v) {
        float4 qw4 = qr[v], aw4 = ar[v];
#pragma unroll
        for (int t = 0; t < T; ++t) {
            float4 t4 = *(const float4*)&tok_s[t][4 * v];
            accq[t] += qw4.x * t4.x + qw4.y * t4.y + qw4.z * t4.z + qw4.w * t4.w;
            acca[t] += aw4.x * t4.x + aw4.y * t4.y + aw4.z * t4.z + aw4.w * t4.w;
        }
    }
    float qb = q_b[c], ab = alpha_b[c];
#pragma unroll
    for (int t = 0; t < T; ++t) {
        size_t idx = ((size_t)t * BS + b) * C + c;
        q_ws[idx] = accq[t] + qb;
        float aa = acca[t] + ab + 3.0f;
        alp_ws[idx] = fminf(fmaxf(aa, 0.0f), 6.0f) * (2.0f / 6.0f);
    }
}

// ---------------------------------------------------------------------------
// Kernel 2: fused attention + mlp via MFMA, split over HW.
// grid = BS*NH*S = 1792; 384 threads = 6 waves.
//   scores: S[t,n] = Q x F     (A=Q b128 frags, B=F strided-u16 frags)
//   PV+MLP: D[c,t~] = F x [P;W] (A=F b128, B=PW b128; t~0-5=O, 6-11=MLP)
// Features staged once per chunk as bf16 [c][n]; K padded 112->128 (zeros).
// ---------------------------------------------------------------------------
__global__ __launch_bounds__(384) void fused_attn_mlp(
    const float* __restrict__ feat,     // [BS,C,HW]
    const float* __restrict__ mlp_w,    // [T,HW]
    const float* __restrict__ q_ws,     // [T,BS,C]
    float* __restrict__ out_attn,       // [BS,NH,T,HW] (pre-softmax scores)
    float* __restrict__ o_part,         // [BS*NH*S][T][DH]
    float* __restrict__ mlp_part,       // [BS*NH*S][T][DH]
    float* __restrict__ ml_part)        // [BS*NH*S][T][2]
{
    int bh = blockIdx.x / S, sp = blockIdx.x % S;
    int b = bh / NH, h = bh % NH;
    int tid = threadIdx.x;
    int wave = tid >> 6, lane = tid & 63;
    int col = lane & 15, quad = lane >> 4;

    __shared__ unsigned short fch[DH][PNF];   // 17.4 KB bf16 features chunk
    __shared__ unsigned short pw[16][PNF];    // 4.4 KB  rows 0-5 = P, 6-11 = W, 12-15 = 0
    __shared__ unsigned short qs[16][QP];     // 2.3 KB  bf16 Q (rows 6-15 = 0)
    __shared__ float st[T][PNS];              // 2.8 KB  fp32 scores chunk
    __shared__ float m_s[T], l_s[T], al_s[T];

    // ---- one-time zero of pads (staging never touches these)
    for (int i = tid; i < 16 * PNF; i += 384) pw[i / PNF][i % PNF] = 0;
    for (int i = tid; i < DH * 24; i += 384) fch[i / 24][112 + (i % 24)] = 0;
    for (int i = tid; i < 16 * QP; i += 384) qs[i / QP][i % QP] = 0;
    if (tid < T) { m_s[tid] = -3e38f; l_s[tid] = 0.f; }
    __syncthreads();
    // ---- stage Q bf16 (rows 0-5)
    for (int i = tid; i < T * DH; i += 384) {
        int t = i / DH, c2 = i % DH;
        qs[t][c2] = f2bf(q_ws[((size_t)t * BS + b) * C + h * DH + c2]);
    }

    const float* fbase = feat + ((size_t)b * C + h * DH) * HW;
    float* obase = out_attn + ((size_t)bh * T) * HW;

    f32x4 accPW = {0.f, 0.f, 0.f, 0.f};    // waves 0-3: [c-tile=wave][t~=col]
    __syncthreads();

    for (int cc = 0; cc < CPB; ++cc) {
        const int n0 = (sp * CPB + cc) * NT;
        // ---- stage f chunk [DH x 112] fp32->bf16
        for (int i = tid; i < DH * (NT / 4); i += 384) {
            int c2 = i / (NT / 4), v = i % (NT / 4);
            float4 f4 = *(const float4*)&fbase[(size_t)c2 * HW + n0 + 4 * v];
            unsigned lo = (unsigned)f2bf(f4.x) | ((unsigned)f2bf(f4.y) << 16);
            unsigned hi = (unsigned)f2bf(f4.z) | ((unsigned)f2bf(f4.w) << 16);
            *(uint2*)&fch[c2][4 * v] = make_uint2(lo, hi);
        }
        // ---- stage mlp_w chunk -> pw rows 6-11
        for (int i = tid; i < T * (NT / 4); i += 384) {
            int t = i / (NT / 4), v = i % (NT / 4);
            float4 f4 = *(const float4*)&mlp_w[(size_t)t * HW + n0 + 4 * v];
            unsigned lo = (unsigned)f2bf(f4.x) | ((unsigned)f2bf(f4.y) << 16);
            unsigned hi = (unsigned)f2bf(f4.z) | ((unsigned)f2bf(f4.w) << 16);
            *(uint2*)&pw[6 + t][4 * v] = make_uint2(lo, hi);
        }
        __syncthreads();

        // ---- scores MFMA: n-tile(s) per wave
        for (int tile = wave; tile < 7; tile += 6) {
            bf16x8 a0 = *(const bf16x8*)&qs[col][quad * 8];
            bf16x8 a1 = *(const bf16x8*)&qs[col][32 + quad * 8];
            bf16x8 b0, b1;
#pragma unroll
            for (int j = 0; j < 8; ++j) {
                b0[j] = (short)fch[quad * 8 + j][tile * 16 + col];
                b1[j] = (short)fch[32 + quad * 8 + j][tile * 16 + col];
            }
            f32x4 acc = {0.f, 0.f, 0.f, 0.f};
            acc = __builtin_amdgcn_mfma_f32_16x16x32_bf16(a0, b0, acc, 0, 0, 0);
            acc = __builtin_amdgcn_mfma_f32_16x16x32_bf16(a1, b1, acc, 0, 0, 0);
#pragma unroll
            for (int reg = 0; reg < 4; ++reg) {
                int r = quad * 4 + reg;
                if (r < 6) st[r][tile * 16 + col] = acc[reg] * SCALE;
            }
        }
        __syncthreads();

        // ---- online softmax (wave t) + coalesced score write-out
        {
            int t = wave;
            float v0 = st[t][lane];
            float v1 = (lane + 64 < NT) ? st[t][lane + 64] : -3e38f;
            float mloc = fmaxf(v0, v1);
#pragma unroll
            for (int off = 32; off; off >>= 1) mloc = fmaxf(mloc, __shfl_down(mloc, off));
            mloc = __shfl(mloc, 0);
            float m_old = m_s[t], m_new = fmaxf(m_old, mloc);
            float p0 = __expf(v0 - m_new);
            float p1 = (lane + 64 < NT) ? __expf(v1 - m_new) : 0.f;
            pw[t][lane] = f2bf(p0);
            if (lane + 64 < NT) pw[t][lane + 64] = f2bf(p1);
            float ssum = p0 + p1;
#pragma unroll
            for (int off = 32; off; off >>= 1) ssum += __shfl_down(ssum, off);
            if (lane == 0) {
                float alpha = __expf(m_old - m_new);
                l_s[t] = l_s[t] * alpha + ssum;
                m_s[t] = m_new;
                al_s[t] = alpha;
            }
            if (lane < NT / 4) {   // coalesced float4 out_attn write
                *(float4*)&obase[(size_t)t * HW + n0 + 4 * lane] =
                    *(const float4*)&st[t][4 * lane];
            }
        }
        __syncthreads();

        // ---- PV + MLP MFMA: wave = c-tile (waves 0-3)
        if (wave < 4) {
            float alpha = (col < 6) ? al_s[col] : 1.0f;
            accPW *= alpha;
#pragma unroll
            for (int ks = 0; ks < 4; ++ks) {
                bf16x8 af = *(const bf16x8*)&fch[wave * 16 + col][ks * 32 + quad * 8];
                bf16x8 bf = *(const bf16x8*)&pw[col][ks * 32 + quad * 8];
                accPW = __builtin_amdgcn_mfma_f32_16x16x32_bf16(af, bf, accPW, 0, 0, 0);
            }
        }
        __syncthreads();   // fch/pw/st reused next chunk
    }

    // ---- epilogue: scatter D tiles to partials
    if (wave < 4) {
#pragma unroll
        for (int reg = 0; reg < 4; ++reg) {
            int c2 = wave * 16 + quad * 4 + reg;   // row = channel
            if (col < 6) {
                o_part[((size_t)blockIdx.x * T + col) * DH + c2] = accPW[reg];
            } else if (col < 12) {
                mlp_part[((size_t)blockIdx.x * T + (col - 6)) * DH + c2] = accPW[reg];
            }
        }
    }
    if (tid < 2 * T) {
        int t = tid >> 1;
        ml_part[((size_t)blockIdx.x * T + t) * 2 + (tid & 1)] =
            (tid & 1) ? l_s[t] : m_s[t];
    }
}

// ---------------------------------------------------------------------------
// Kernel 3: merge split partials + gate + proj + residual + LayerNorm.
// ---------------------------------------------------------------------------
__global__ __launch_bounds__(256) void merge_proj_ln_kernel(
    const float* __restrict__ o_part,
    const float* __restrict__ mlp_part,
    const float* __restrict__ ml_part,
    const float* __restrict__ mlp_b,    // [T]
    const float* __restrict__ alp_ws,   // [T,BS,C]
    const float* __restrict__ tokens,   // [T,BS,D]
    const float* __restrict__ proj_w,   // [D,C]
    const float* __restrict__ proj_b,   // [D]
    const float* __restrict__ ln_g,     // [D]
    const float* __restrict__ ln_b,     // [D]
    float* __restrict__ out_tok)        // [T,BS,D]
{
    int tb = blockIdx.x;
    int t = tb / BS, b = tb % BS;
    int tid = threadIdx.x;
    __shared__ float g_s[C];
    __shared__ float r1[4], r2[4];

    {
        int c = tid;
        int h = c >> 6, cl = c & 63;
        int bh = b * NH + h;
        float m[S], l[S];
        float M = -3e38f;
#pragma unroll
        for (int s = 0; s < S; ++s) {
            size_t blk = (size_t)(bh * S + s);
            m[s] = ml_part[(blk * T + t) * 2 + 0];
            l[s] = ml_part[(blk * T + t) * 2 + 1];
            M = fmaxf(M, m[s]);
        }
        float L = 0.f, O = 0.f, MLP = 0.f;
#pragma unroll
        for (int s = 0; s < S; ++s) {
            float w = __expf(m[s] - M);
            size_t blk = (size_t)(bh * S + s);
            size_t pidx = (blk * T + t) * DH + cl;
            L += l[s] * w;
            O += o_part[pidx] * w;
            MLP += mlp_part[pidx];
        }
        size_t idx = (size_t)tb * C + c;
        g_s[c] = (MLP + mlp_b[t] + O / L) * alp_ws[idx];
    }
    __syncthreads();

    if (tid < D) {
        int d = tid;
        float acc = proj_b[d] + tokens[(size_t)tb * D + d];
        const float4* pr = (const float4*)(proj_w + (size_t)d * C);
#pragma unroll 8
        for (int v = 0; v < C / 4; ++v) {
            float4 w4 = pr[v];
            float4 g4 = *(const float4*)&g_s[4 * v];
            acc += w4.x * g4.x + w4.y * g4.y + w4.z * g4.z + w4.w * g4.w;
        }

        float s1 = acc, s2 = acc * acc;
#pragma unroll
        for (int off = 32; off; off >>= 1) { s1 += __shfl_down(s1, off); s2 += __shfl_down(s2, off); }
        int wv = d >> 6, lane = d & 63;
        if (lane == 0) { r1[wv] = s1; r2[wv] = s2; }
        __syncthreads();
        float sum1 = r1[0] + r1[1] + r1[2];
        float sum2 = r2[0] + r2[1] + r2[2];
        float mu = sum1 * (1.0f / D);
        float var = sum2 * (1.0f / D) - mu * mu;
        float inv = rsqrtf(var + LN_EPS);
        out_tok[(size_t)tb * D + d] = (acc - mu) * inv * ln_g[d] + ln_b[d];
    } else {
        __syncthreads();
    }
}

// ---------------------------------------------------------------------------
extern "C" void kernel_launch(void* const* d_in, const int* in_sizes, int n_in,
                              void* d_out, int out_size, void* d_ws, size_t ws_size,
                              hipStream_t stream) {
    const float* features = (const float*)d_in[0];
    const float* tokens   = (const float*)d_in[1];
    const float* mlp_w    = (const float*)d_in[2];
    const float* mlp_b    = (const float*)d_in[3];
    const float* q_w      = (const float*)d_in[4];
    const float* q_b      = (const float*)d_in[5];
    const float* alpha_w  = (const float*)d_in[6];
    const float* alpha_b  = (const float*)d_in[7];
    const float* proj_w   = (const float*)d_in[8];
    const float* proj_b   = (const float*)d_in[9];
    const float* ln_g     = (const float*)d_in[10];
    const float* ln_b     = (const float*)d_in[11];

    float* out_tok  = (float*)d_out;                   // [T,BS,D]
    float* out_attn = (float*)d_out + T * BS * D;      // [BS,NH,T,HW]

    constexpr int NBLK = BS * NH * S;                  // 1792
    float* q_ws     = (float*)d_ws;                    // T*BS*C
    float* alp_ws   = q_ws + T * BS * C;               // T*BS*C
    float* ml_part  = alp_ws + T * BS * C;             // NBLK*T*2
    float* o_part   = ml_part + NBLK * T * 2;          // NBLK*T*DH
    float* mlp_part = o_part + NBLK * T * DH;          // NBLK*T*DH

    qalpha_kernel<<<BS, 256, 0, stream>>>(
        tokens, q_w, q_b, alpha_w, alpha_b, q_ws, alp_ws);

    fused_attn_mlp<<<NBLK, 384, 0, stream>>>(
        features, mlp_w, q_ws, out_attn, o_part, mlp_part, ml_part);

    merge_proj_ln_kernel<<<T * BS, 256, 0, stream>>>(
        o_part, mlp_part, ml_part, mlp_b, alp_ws, tokens,
        proj_w, proj_b, ln_g, ln_b, out_tok);
}